// Round 5
// baseline (342.111 us; speedup 1.0000x reference)
//
#include <hip/hip_runtime.h>

// Newton-Schulz matrix sqrt, 1024 batches of 128x128 SPD, 5 iterations.
// R9 = R8 + __launch_bounds__(1024, 4)  [single-variable change].
// R8 post-mortem: launch_bounds(1024,1) let the compiler allocate for
// 32-waves/CU occupancy -> 64 VGPRs/wave; live state ~110 regs -> spill
// (FETCH +143MB, WRITE +80MB scratch traffic, dur 186->279). LDS caps us
// at 1 block/CU anyway, so min-waves/EU=4 (k = 4*4/16 = 1 block/CU)
// raises the budget to 128 VGPRs (512/SIMD / 4 waves) -> no spill, and
// properly tests the R8 occupancy theory (4 waves/SIMD vs R7's 2).
// Everything else identical to R8:
//   - 16 waves (4x4 grid), 32x32 slab/wave, 4 batches/block, grid 256
//   - Tq double-buffered, one barrier per phase; XOR-swizzled LDS;
//     red[] aliases Tq buf1; split_pair; s_setprio around MFMA.

#define NN 128

typedef short bf16x8  __attribute__((ext_vector_type(8)));
typedef short short4v __attribute__((ext_vector_type(4)));
typedef float f32x4   __attribute__((ext_vector_type(4)));

__device__ __forceinline__ float bf2f(short h) {
  union { unsigned u; float f; } c;
  c.u = ((unsigned)(unsigned short)h) << 16;
  return c.f;
}

// D[15:0] = bf16_rne(a), D[31:16] = bf16_rne(b)
__device__ __forceinline__ unsigned cvt_pk_bf16(float a, float b) {
  unsigned r;
  asm("v_cvt_pk_bf16_f32 %0, %1, %2" : "=v"(r) : "v"(a), "v"(b));
  return r;
}

// hp = {trunc16(x1), trunc16(x0)} (1 v_perm_b32);
// lp = {rne16(x1-hi1), rne16(x0-hi0)} (2 and, 2 sub, 1 cvt_pk).
__device__ __forceinline__ void split_pair(float x0, float x1,
                                           unsigned& hp, unsigned& lp) {
  union { float f; unsigned u; } c0, c1; c0.f = x0; c1.f = x1;
  hp = __builtin_amdgcn_perm(c1.u, c0.u, 0x07060302u);
  union { unsigned u; float f; } h0, h1;
  h0.u = c0.u & 0xFFFF0000u;
  h1.u = c1.u & 0xFFFF0000u;
  lp = cvt_pk_bf16(x0 - h0.f, x1 - h1.f);
}

// Swizzled LDS index helpers (index in shorts).
// Y/Z: [R][K], 128x128, unit = K>>3 (16B), unit ^= (R&7).
__device__ __forceinline__ int yix2(int R, int K) {
  return (R << 7) + (((K >> 3) ^ (R & 7)) << 3) + (K & 7);
}
// Tq: [C][K], 128x32, unit = K>>3 (0..3), unit ^= (C&3).
__device__ __forceinline__ int tix(int C, int K) {
  return (C << 5) + (((K >> 3) ^ (C & 3)) << 3) + (K & 7);
}

#define YIX(R, K) yix2((R), (K))

#define MFMA3(ACC, AH, AL, BH, BL)                                        \
  ACC = __builtin_amdgcn_mfma_f32_16x16x32_bf16(AH, BH, ACC, 0, 0, 0);    \
  ACC = __builtin_amdgcn_mfma_f32_16x16x32_bf16(AH, BL, ACC, 0, 0, 0);    \
  ACC = __builtin_amdgcn_mfma_f32_16x16x32_bf16(AL, BH, ACC, 0, 0, 0);

__global__ __launch_bounds__(1024, 4)
void ns_sqrt_kernel(const float* __restrict__ A, float* __restrict__ out) {
  __shared__ __align__(16) short Yhi[NN * NN];
  __shared__ __align__(16) short Ylo[NN * NN];
  __shared__ __align__(16) short Zhi[NN * NN];
  __shared__ __align__(16) short Zlo[NN * NN];
  __shared__ __align__(16) short Tq[2][2][NN * 32];  // [buf][hi=0/lo=1]

  // 163,840 B total == exactly the 160 KiB cap; red aliases Tq buf1.
  float* red = reinterpret_cast<float*>(&Tq[1][0][0]);

  const int tid  = threadIdx.x;
  const int wave = tid >> 6;
  const int lane = tid & 63;
  const int quad = lane >> 4;
  const int lrow = lane & 15;
  const int wr = wave >> 2, wc = wave & 3;
  const int RB = wr << 5, CB = wc << 5;   // 32x32 slab base

  #pragma unroll 1
  for (int sb = 0; sb < 4; ++sb) {
    const int b = (blockIdx.x << 2) + sb;
    const float* Ab = A + (size_t)b * (NN * NN);

    // ---- init: load all of A, Frobenius sum, store unnormalized split A ----
    float ss = 0.f;
    {
      const float4* p = reinterpret_cast<const float4*>(Ab);
      #pragma unroll
      for (int k = 0; k < 4; ++k) {
        const int idx = tid + (k << 10);   // float4 index, lane-consecutive
        float4 v = p[idx];
        ss += v.x * v.x + v.y * v.y + v.z * v.z + v.w * v.w;
        unsigned h01, l01, h23, l23;
        split_pair(v.x, v.y, h01, l01);
        split_pair(v.z, v.w, h23, l23);
        const int row = idx >> 5;
        const int cc  = (idx & 31) << 2;
        const int o = YIX(row, cc);
        *(uint2*)&Yhi[o] = make_uint2(h01, h23);
        *(uint2*)&Ylo[o] = make_uint2(l01, l23);
      }
    }
    #pragma unroll
    for (int off = 32; off; off >>= 1) ss += __shfl_xor(ss, off, 64);
    if (lane == 0) red[wave] = ss;
    __syncthreads();
    float tot = 0.f;
    #pragma unroll
    for (int w = 0; w < 16; ++w) tot += red[w];
    const float normA = sqrtf(tot);
    const float rn    = 1.f / normA;
    const float s_out = sqrtf(normA);

    const f32x4 zero4 = {0.f, 0.f, 0.f, 0.f};

    #pragma unroll 1
    for (int it = 1; it <= 5; ++it) {
      const bool doQ = (it >= 2) && (it <= 4);   // it1: Z1 = T; it5: Z unused
      f32x4 accM[2][2];
      f32x4 accP[2][2];
      f32x4 accQ[2][2];
      #pragma unroll
      for (int i = 0; i < 2; ++i)
        #pragma unroll
        for (int j = 0; j < 2; ++j) { accP[i][j] = zero4; accQ[i][j] = zero4; }

      if (it == 1) {
        // M = A slab (symmetric b64 read); normalization folded via mscale
        #pragma unroll
        for (int i = 0; i < 2; ++i)
          #pragma unroll
          for (int j = 0; j < 2; ++j) {
            const int col  = CB + 16*j + lrow;
            const int row0 = RB + 16*i + (quad << 2);
            const int o = YIX(col, row0);
            short4v h = *(const short4v*)&Yhi[o];
            short4v l = *(const short4v*)&Ylo[o];
            #pragma unroll
            for (int r = 0; r < 4; ++r) accM[i][j][r] = bf2f(h[r]) + bf2f(l[r]);
          }
      } else {
        // M = Z*Y  (A = Z rows; B = Y rows via symmetry)
        #pragma unroll
        for (int i = 0; i < 2; ++i)
          #pragma unroll
          for (int j = 0; j < 2; ++j) accM[i][j] = zero4;
        #pragma unroll
        for (int kc = 0; kc < 4; ++kc) {
          const int k0 = (kc << 5) + (quad << 3);
          bf16x8 ah[2], al[2], bh[2], bl[2];
          #pragma unroll
          for (int i = 0; i < 2; ++i) {
            const int o = YIX(RB + lrow + 16*i, k0);
            ah[i] = *(const bf16x8*)&Zhi[o];
            al[i] = *(const bf16x8*)&Zlo[o];
          }
          #pragma unroll
          for (int j = 0; j < 2; ++j) {
            const int o = YIX(CB + lrow + 16*j, k0);
            bh[j] = *(const bf16x8*)&Yhi[o];
            bl[j] = *(const bf16x8*)&Ylo[o];
          }
          #pragma unroll
          for (int i = 0; i < 2; ++i)
            #pragma unroll
            for (int j = 0; j < 2; ++j) { MFMA3(accM[i][j], ah[i], al[i], bh[j], bl[j]); }
        }
      }

      // T = 1.5 I - 0.5*mscale*M, split immediately into packed regs
      const float mscale = (it == 1) ? rn : 1.0f;
      unsigned tp[2][2][2], tl[2][2][2];
      #pragma unroll
      for (int i = 0; i < 2; ++i)
        #pragma unroll
        for (int j = 0; j < 2; ++j) {
          float tv[4];
          #pragma unroll
          for (int r = 0; r < 4; ++r) {
            float t0 = -0.5f * mscale * accM[i][j][r];
            if (RB + 16*i + (quad << 2) + r == CB + 16*j + lrow) t0 += 1.5f;
            tv[r] = t0;
          }
          split_pair(tv[0], tv[1], tp[i][j][0], tl[i][j][0]);
          split_pair(tv[2], tv[3], tp[i][j][1], tl[i][j][1]);
        }

      // 4 phases over 32-row blocks of T, double-buffered panels.
      // Phase t: the 4 waves with wr==t stage buf[t&1] (prev readers
      // drained at barrier t-1), ONE publish barrier, everyone computes.
      #pragma unroll 1
      for (int t = 0; t < 4; ++t) {
        short* __restrict__ th = &Tq[t & 1][0][0];
        short* __restrict__ tg = &Tq[t & 1][1][0];

        if (wr == t) {
          #pragma unroll
          for (int i = 0; i < 2; ++i) {
            const int kp0 = (i << 4) + (quad << 2);
            #pragma unroll
            for (int j = 0; j < 2; ++j) {
              const int col = CB + 16*j + lrow;
              const int o = tix(col, kp0);
              *(uint2*)&th[o] = make_uint2(tp[i][j][0], tp[i][j][1]);
              *(uint2*)&tg[o] = make_uint2(tl[i][j][0], tl[i][j][1]);
            }
          }
        }

        // A-fragments depend only on Y/Z (stable all phase-loop long):
        // issued above the barrier so their latency hides under the wait.
        const int k0 = (t << 5) + (quad << 3);
        bf16x8 ahY[2], alY[2], ahZ[2], alZ[2];
        #pragma unroll
        for (int i = 0; i < 2; ++i) {
          const int o = YIX(RB + lrow + 16*i, k0);
          ahY[i] = *(const bf16x8*)&Yhi[o];
          alY[i] = *(const bf16x8*)&Ylo[o];
        }
        if (doQ) {
          #pragma unroll
          for (int i = 0; i < 2; ++i) {
            const int o = YIX(RB + lrow + 16*i, k0);
            ahZ[i] = *(const bf16x8*)&Zhi[o];
            alZ[i] = *(const bf16x8*)&Zlo[o];
          }
        }

        __syncthreads();                   // publish Tq[t&1]

        const int kq = quad << 3;
        bf16x8 bh[2], bl[2];
        #pragma unroll
        for (int j = 0; j < 2; ++j) {
          const int o = tix(CB + 16*j + lrow, kq);
          bh[j] = *(const bf16x8*)&th[o];
          bl[j] = *(const bf16x8*)&tg[o];
        }
        __builtin_amdgcn_s_setprio(1);
        #pragma unroll
        for (int i = 0; i < 2; ++i)
          #pragma unroll
          for (int j = 0; j < 2; ++j) { MFMA3(accP[i][j], ahY[i], alY[i], bh[j], bl[j]); }
        if (doQ) {
          #pragma unroll
          for (int i = 0; i < 2; ++i)
            #pragma unroll
            for (int j = 0; j < 2; ++j) { MFMA3(accQ[i][j], ahZ[i], alZ[i], bh[j], bl[j]); }
        }
        __builtin_amdgcn_s_setprio(0);
      }
      __syncthreads();   // all reads of Y/Z/Tq complete

      if (it < 5) {
        // write-back (packed b64 "transposed" store = same matrix by symmetry)
        const float yscale = (it == 1) ? rn : 1.0f;
        #pragma unroll
        for (int i = 0; i < 2; ++i)
          #pragma unroll
          for (int j = 0; j < 2; ++j) {
            const int col  = CB + 16*j + lrow;
            const int row0 = RB + 16*i + (quad << 2);
            const int o = YIX(col, row0);
            unsigned h01, l01, h23, l23;
            split_pair(yscale * accP[i][j][0], yscale * accP[i][j][1], h01, l01);
            split_pair(yscale * accP[i][j][2], yscale * accP[i][j][3], h23, l23);
            *(uint2*)&Yhi[o] = make_uint2(h01, h23);
            *(uint2*)&Ylo[o] = make_uint2(l01, l23);
            if (it == 1) {
              // Z1 = T: reuse the packed split regs directly
              *(uint2*)&Zhi[o] = make_uint2(tp[i][j][0], tp[i][j][1]);
              *(uint2*)&Zlo[o] = make_uint2(tl[i][j][0], tl[i][j][1]);
            } else {
              split_pair(accQ[i][j][0], accQ[i][j][1], h01, l01);
              split_pair(accQ[i][j][2], accQ[i][j][3], h23, l23);
              *(uint2*)&Zhi[o] = make_uint2(h01, h23);
              *(uint2*)&Zlo[o] = make_uint2(l01, l23);
            }
          }
        __syncthreads();
      } else {
        // final: out = Y5 * sqrt(normA)  (fire-and-forget; overlaps next init)
        float* ob = out + (size_t)b * (NN * NN);
        #pragma unroll
        for (int i = 0; i < 2; ++i)
          #pragma unroll
          for (int j = 0; j < 2; ++j) {
            const int col  = CB + 16*j + lrow;
            const int row0 = RB + 16*i + (quad << 2);
            #pragma unroll
            for (int r = 0; r < 4; ++r)
              ob[(size_t)(row0 + r) * NN + col] = accP[i][j][r] * s_out;
          }
      }
    }
  }
}

extern "C" void kernel_launch(void* const* d_in, const int* in_sizes, int n_in,
                              void* d_out, int out_size, void* d_ws, size_t ws_size,
                              hipStream_t stream) {
  const float* A = (const float*)d_in[0];
  float* out = (float*)d_out;
  ns_sqrt_kernel<<<dim3(256), dim3(1024), 0, stream>>>(A, out);
}

// Round 6
// 338.316 us; speedup vs baseline: 1.0112x; 1.0112x over previous
//
#include <hip/hip_runtime.h>

// Newton-Schulz matrix sqrt, 1024 batches of 128x128 SPD, 5 iterations.
// R10 = R9 + amdgpu_waves_per_eu(4,4)  [single-variable change].
// R9 post-mortem: __launch_bounds__(B, w) sets waves-per-eu MINIMUM only;
// the backend heuristic still TARGETED 8 waves/EU (ignoring that 160KiB
// LDS caps residency at 1 block = 4 waves/SIMD), allocated 64 VGPRs, and
// spilled ~50 regs/thread (FETCH 178MB, WRITE 149MB scratch; R9 == R8
// byte-for-byte: VGPR 64, dur 279 both). Clamping max waves/EU to 4
// raises the allocator budget to 512/4 = 128 VGPRs -> no spill; max=4 is
// free because LDS pins us at 4 waves/SIMD anyway.
// This is the clean test of the R8 occupancy theory (4 vs 2 waves/SIMD).
// Everything else identical to R8/R9:
//   - 16 waves (4x4 grid), 32x32 slab/wave, 4 batches/block, grid 256
//   - Tq double-buffered, one barrier per phase; XOR-swizzled LDS;
//     red[] aliases Tq buf1; split_pair; s_setprio around MFMA.

#define NN 128

typedef short bf16x8  __attribute__((ext_vector_type(8)));
typedef short short4v __attribute__((ext_vector_type(4)));
typedef float f32x4   __attribute__((ext_vector_type(4)));

__device__ __forceinline__ float bf2f(short h) {
  union { unsigned u; float f; } c;
  c.u = ((unsigned)(unsigned short)h) << 16;
  return c.f;
}

// D[15:0] = bf16_rne(a), D[31:16] = bf16_rne(b)
__device__ __forceinline__ unsigned cvt_pk_bf16(float a, float b) {
  unsigned r;
  asm("v_cvt_pk_bf16_f32 %0, %1, %2" : "=v"(r) : "v"(a), "v"(b));
  return r;
}

// hp = {trunc16(x1), trunc16(x0)} (1 v_perm_b32);
// lp = {rne16(x1-hi1), rne16(x0-hi0)} (2 and, 2 sub, 1 cvt_pk).
__device__ __forceinline__ void split_pair(float x0, float x1,
                                           unsigned& hp, unsigned& lp) {
  union { float f; unsigned u; } c0, c1; c0.f = x0; c1.f = x1;
  hp = __builtin_amdgcn_perm(c1.u, c0.u, 0x07060302u);
  union { unsigned u; float f; } h0, h1;
  h0.u = c0.u & 0xFFFF0000u;
  h1.u = c1.u & 0xFFFF0000u;
  lp = cvt_pk_bf16(x0 - h0.f, x1 - h1.f);
}

// Swizzled LDS index helpers (index in shorts).
// Y/Z: [R][K], 128x128, unit = K>>3 (16B), unit ^= (R&7).
__device__ __forceinline__ int yix2(int R, int K) {
  return (R << 7) + (((K >> 3) ^ (R & 7)) << 3) + (K & 7);
}
// Tq: [C][K], 128x32, unit = K>>3 (0..3), unit ^= (C&3).
__device__ __forceinline__ int tix(int C, int K) {
  return (C << 5) + (((K >> 3) ^ (C & 3)) << 3) + (K & 7);
}

#define YIX(R, K) yix2((R), (K))

#define MFMA3(ACC, AH, AL, BH, BL)                                        \
  ACC = __builtin_amdgcn_mfma_f32_16x16x32_bf16(AH, BH, ACC, 0, 0, 0);    \
  ACC = __builtin_amdgcn_mfma_f32_16x16x32_bf16(AH, BL, ACC, 0, 0, 0);    \
  ACC = __builtin_amdgcn_mfma_f32_16x16x32_bf16(AL, BH, ACC, 0, 0, 0);

__global__ __launch_bounds__(1024)
__attribute__((amdgpu_waves_per_eu(4, 4)))
void ns_sqrt_kernel(const float* __restrict__ A, float* __restrict__ out) {
  __shared__ __align__(16) short Yhi[NN * NN];
  __shared__ __align__(16) short Ylo[NN * NN];
  __shared__ __align__(16) short Zhi[NN * NN];
  __shared__ __align__(16) short Zlo[NN * NN];
  __shared__ __align__(16) short Tq[2][2][NN * 32];  // [buf][hi=0/lo=1]

  // 163,840 B total == exactly the 160 KiB cap; red aliases Tq buf1.
  float* red = reinterpret_cast<float*>(&Tq[1][0][0]);

  const int tid  = threadIdx.x;
  const int wave = tid >> 6;
  const int lane = tid & 63;
  const int quad = lane >> 4;
  const int lrow = lane & 15;
  const int wr = wave >> 2, wc = wave & 3;
  const int RB = wr << 5, CB = wc << 5;   // 32x32 slab base

  #pragma unroll 1
  for (int sb = 0; sb < 4; ++sb) {
    const int b = (blockIdx.x << 2) + sb;
    const float* Ab = A + (size_t)b * (NN * NN);

    // ---- init: load all of A, Frobenius sum, store unnormalized split A ----
    float ss = 0.f;
    {
      const float4* p = reinterpret_cast<const float4*>(Ab);
      #pragma unroll
      for (int k = 0; k < 4; ++k) {
        const int idx = tid + (k << 10);   // float4 index, lane-consecutive
        float4 v = p[idx];
        ss += v.x * v.x + v.y * v.y + v.z * v.z + v.w * v.w;
        unsigned h01, l01, h23, l23;
        split_pair(v.x, v.y, h01, l01);
        split_pair(v.z, v.w, h23, l23);
        const int row = idx >> 5;
        const int cc  = (idx & 31) << 2;
        const int o = YIX(row, cc);
        *(uint2*)&Yhi[o] = make_uint2(h01, h23);
        *(uint2*)&Ylo[o] = make_uint2(l01, l23);
      }
    }
    #pragma unroll
    for (int off = 32; off; off >>= 1) ss += __shfl_xor(ss, off, 64);
    if (lane == 0) red[wave] = ss;
    __syncthreads();
    float tot = 0.f;
    #pragma unroll
    for (int w = 0; w < 16; ++w) tot += red[w];
    const float normA = sqrtf(tot);
    const float rn    = 1.f / normA;
    const float s_out = sqrtf(normA);

    const f32x4 zero4 = {0.f, 0.f, 0.f, 0.f};

    #pragma unroll 1
    for (int it = 1; it <= 5; ++it) {
      const bool doQ = (it >= 2) && (it <= 4);   // it1: Z1 = T; it5: Z unused
      f32x4 accM[2][2];
      f32x4 accP[2][2];
      f32x4 accQ[2][2];
      #pragma unroll
      for (int i = 0; i < 2; ++i)
        #pragma unroll
        for (int j = 0; j < 2; ++j) { accP[i][j] = zero4; accQ[i][j] = zero4; }

      if (it == 1) {
        // M = A slab (symmetric b64 read); normalization folded via mscale
        #pragma unroll
        for (int i = 0; i < 2; ++i)
          #pragma unroll
          for (int j = 0; j < 2; ++j) {
            const int col  = CB + 16*j + lrow;
            const int row0 = RB + 16*i + (quad << 2);
            const int o = YIX(col, row0);
            short4v h = *(const short4v*)&Yhi[o];
            short4v l = *(const short4v*)&Ylo[o];
            #pragma unroll
            for (int r = 0; r < 4; ++r) accM[i][j][r] = bf2f(h[r]) + bf2f(l[r]);
          }
      } else {
        // M = Z*Y  (A = Z rows; B = Y rows via symmetry)
        #pragma unroll
        for (int i = 0; i < 2; ++i)
          #pragma unroll
          for (int j = 0; j < 2; ++j) accM[i][j] = zero4;
        #pragma unroll
        for (int kc = 0; kc < 4; ++kc) {
          const int k0 = (kc << 5) + (quad << 3);
          bf16x8 ah[2], al[2], bh[2], bl[2];
          #pragma unroll
          for (int i = 0; i < 2; ++i) {
            const int o = YIX(RB + lrow + 16*i, k0);
            ah[i] = *(const bf16x8*)&Zhi[o];
            al[i] = *(const bf16x8*)&Zlo[o];
          }
          #pragma unroll
          for (int j = 0; j < 2; ++j) {
            const int o = YIX(CB + lrow + 16*j, k0);
            bh[j] = *(const bf16x8*)&Yhi[o];
            bl[j] = *(const bf16x8*)&Ylo[o];
          }
          #pragma unroll
          for (int i = 0; i < 2; ++i)
            #pragma unroll
            for (int j = 0; j < 2; ++j) { MFMA3(accM[i][j], ah[i], al[i], bh[j], bl[j]); }
        }
      }

      // T = 1.5 I - 0.5*mscale*M, split immediately into packed regs
      const float mscale = (it == 1) ? rn : 1.0f;
      unsigned tp[2][2][2], tl[2][2][2];
      #pragma unroll
      for (int i = 0; i < 2; ++i)
        #pragma unroll
        for (int j = 0; j < 2; ++j) {
          float tv[4];
          #pragma unroll
          for (int r = 0; r < 4; ++r) {
            float t0 = -0.5f * mscale * accM[i][j][r];
            if (RB + 16*i + (quad << 2) + r == CB + 16*j + lrow) t0 += 1.5f;
            tv[r] = t0;
          }
          split_pair(tv[0], tv[1], tp[i][j][0], tl[i][j][0]);
          split_pair(tv[2], tv[3], tp[i][j][1], tl[i][j][1]);
        }

      // 4 phases over 32-row blocks of T, double-buffered panels.
      // Phase t: the 4 waves with wr==t stage buf[t&1] (prev readers
      // drained at barrier t-1), ONE publish barrier, everyone computes.
      #pragma unroll 1
      for (int t = 0; t < 4; ++t) {
        short* __restrict__ th = &Tq[t & 1][0][0];
        short* __restrict__ tg = &Tq[t & 1][1][0];

        if (wr == t) {
          #pragma unroll
          for (int i = 0; i < 2; ++i) {
            const int kp0 = (i << 4) + (quad << 2);
            #pragma unroll
            for (int j = 0; j < 2; ++j) {
              const int col = CB + 16*j + lrow;
              const int o = tix(col, kp0);
              *(uint2*)&th[o] = make_uint2(tp[i][j][0], tp[i][j][1]);
              *(uint2*)&tg[o] = make_uint2(tl[i][j][0], tl[i][j][1]);
            }
          }
        }

        // A-fragments depend only on Y/Z (stable all phase-loop long):
        // issued above the barrier so their latency hides under the wait.
        const int k0 = (t << 5) + (quad << 3);
        bf16x8 ahY[2], alY[2], ahZ[2], alZ[2];
        #pragma unroll
        for (int i = 0; i < 2; ++i) {
          const int o = YIX(RB + lrow + 16*i, k0);
          ahY[i] = *(const bf16x8*)&Yhi[o];
          alY[i] = *(const bf16x8*)&Ylo[o];
        }
        if (doQ) {
          #pragma unroll
          for (int i = 0; i < 2; ++i) {
            const int o = YIX(RB + lrow + 16*i, k0);
            ahZ[i] = *(const bf16x8*)&Zhi[o];
            alZ[i] = *(const bf16x8*)&Zlo[o];
          }
        }

        __syncthreads();                   // publish Tq[t&1]

        const int kq = quad << 3;
        bf16x8 bh[2], bl[2];
        #pragma unroll
        for (int j = 0; j < 2; ++j) {
          const int o = tix(CB + 16*j + lrow, kq);
          bh[j] = *(const bf16x8*)&th[o];
          bl[j] = *(const bf16x8*)&tg[o];
        }
        __builtin_amdgcn_s_setprio(1);
        #pragma unroll
        for (int i = 0; i < 2; ++i)
          #pragma unroll
          for (int j = 0; j < 2; ++j) { MFMA3(accP[i][j], ahY[i], alY[i], bh[j], bl[j]); }
        if (doQ) {
          #pragma unroll
          for (int i = 0; i < 2; ++i)
            #pragma unroll
            for (int j = 0; j < 2; ++j) { MFMA3(accQ[i][j], ahZ[i], alZ[i], bh[j], bl[j]); }
        }
        __builtin_amdgcn_s_setprio(0);
      }
      __syncthreads();   // all reads of Y/Z/Tq complete

      if (it < 5) {
        // write-back (packed b64 "transposed" store = same matrix by symmetry)
        const float yscale = (it == 1) ? rn : 1.0f;
        #pragma unroll
        for (int i = 0; i < 2; ++i)
          #pragma unroll
          for (int j = 0; j < 2; ++j) {
            const int col  = CB + 16*j + lrow;
            const int row0 = RB + 16*i + (quad << 2);
            const int o = YIX(col, row0);
            unsigned h01, l01, h23, l23;
            split_pair(yscale * accP[i][j][0], yscale * accP[i][j][1], h01, l01);
            split_pair(yscale * accP[i][j][2], yscale * accP[i][j][3], h23, l23);
            *(uint2*)&Yhi[o] = make_uint2(h01, h23);
            *(uint2*)&Ylo[o] = make_uint2(l01, l23);
            if (it == 1) {
              // Z1 = T: reuse the packed split regs directly
              *(uint2*)&Zhi[o] = make_uint2(tp[i][j][0], tp[i][j][1]);
              *(uint2*)&Zlo[o] = make_uint2(tl[i][j][0], tl[i][j][1]);
            } else {
              split_pair(accQ[i][j][0], accQ[i][j][1], h01, l01);
              split_pair(accQ[i][j][2], accQ[i][j][3], h23, l23);
              *(uint2*)&Zhi[o] = make_uint2(h01, h23);
              *(uint2*)&Zlo[o] = make_uint2(l01, l23);
            }
          }
        __syncthreads();
      } else {
        // final: out = Y5 * sqrt(normA)  (fire-and-forget; overlaps next init)
        float* ob = out + (size_t)b * (NN * NN);
        #pragma unroll
        for (int i = 0; i < 2; ++i)
          #pragma unroll
          for (int j = 0; j < 2; ++j) {
            const int col  = CB + 16*j + lrow;
            const int row0 = RB + 16*i + (quad << 2);
            #pragma unroll
            for (int r = 0; r < 4; ++r)
              ob[(size_t)(row0 + r) * NN + col] = accP[i][j][r] * s_out;
          }
      }
    }
  }
}

extern "C" void kernel_launch(void* const* d_in, const int* in_sizes, int n_in,
                              void* d_out, int out_size, void* d_ws, size_t ws_size,
                              hipStream_t stream) {
  const float* A = (const float*)d_in[0];
  float* out = (float*)d_out;
  ns_sqrt_kernel<<<dim3(256), dim3(1024), 0, stream>>>(A, out);
}

// Round 7
// 233.121 us; speedup vs baseline: 1.4675x; 1.4512x over previous
//
#include <hip/hip_runtime.h>

// Newton-Schulz matrix sqrt, 1024 batches of 128x128 SPD, 5 iterations.
// R11 = R7 (186us verified: 8 waves, 512 thr, VGPR 128, no spill)
//       + Tq swizzle fix [single change]: u ^= (C>>1)&3  (was C&3).
// R8-R10 post-mortem: 1024-thr shape unfixable (backend pins 64 VGPR and
// spills ~50 regs/thread regardless of launch_bounds/waves_per_eu; FETCH
// 178MB WRITE 149MB scratch, 279us). Abandoned; back to R7 shape.
// R11 theory: LDS serves b128 at 128B/cy = 8 lanes/pass; conflict freedom
// must hold per 8-lane pass. Tq rows are 64B = 16 banks, so bank-group =
// (C&1, (K>>3)^(C&3)); lanes lrow and lrow+4 share both -> 2-way conflict
// on every Tq B-frag read (introduced in R5 when SQ=40 padding was
// dropped; conflict counter 2.36e7->2.88e7 corroborates). New u-term
// (C>>1)&3 makes (C&1, u) enumerate all 8 bank-groups across 8
// consecutive C. Stager + reader share tix -> layout-invariant.
// Everything else identical to R7:
//   - Tq double-buffered, one barrier per phase; phase loop unroll 1
//   - Y/Z XOR-swizzle unit^=(R&7) (audited pass-perfect)
//   - red[] aliases Tq buf1; split_pair; s_setprio around MFMA.

#define NN 128

typedef short bf16x8  __attribute__((ext_vector_type(8)));
typedef short short4v __attribute__((ext_vector_type(4)));
typedef float f32x4   __attribute__((ext_vector_type(4)));

__device__ __forceinline__ float bf2f(short h) {
  union { unsigned u; float f; } c;
  c.u = ((unsigned)(unsigned short)h) << 16;
  return c.f;
}

// D[15:0] = bf16_rne(a), D[31:16] = bf16_rne(b)
__device__ __forceinline__ unsigned cvt_pk_bf16(float a, float b) {
  unsigned r;
  asm("v_cvt_pk_bf16_f32 %0, %1, %2" : "=v"(r) : "v"(a), "v"(b));
  return r;
}

// hp = {trunc16(x1), trunc16(x0)} (1 v_perm_b32);
// lp = {rne16(x1-hi1), rne16(x0-hi0)} (2 and, 2 sub, 1 cvt_pk).
__device__ __forceinline__ void split_pair(float x0, float x1,
                                           unsigned& hp, unsigned& lp) {
  union { float f; unsigned u; } c0, c1; c0.f = x0; c1.f = x1;
  hp = __builtin_amdgcn_perm(c1.u, c0.u, 0x07060302u);
  union { unsigned u; float f; } h0, h1;
  h0.u = c0.u & 0xFFFF0000u;
  h1.u = c1.u & 0xFFFF0000u;
  lp = cvt_pk_bf16(x0 - h0.f, x1 - h1.f);
}

// Swizzled LDS index helpers (index in shorts).
// Y/Z: [R][K], 128x128, unit = K>>3 (16B), unit ^= (R&7).
__device__ __forceinline__ int yix2(int R, int K) {
  return (R << 7) + (((K >> 3) ^ (R & 7)) << 3) + (K & 7);
}
// Tq: [C][K], 128x32, unit = K>>3 (0..3), unit ^= ((C>>1)&3).
// (C&1 selects the 16-bank half via the row base; (C>>1)&3 walks the
//  4 units -> 8 consecutive C cover all 8 bank-groups per pass.)
__device__ __forceinline__ int tix(int C, int K) {
  return (C << 5) + ((((K >> 3) ^ (C >> 1)) & 3) << 3) + (K & 7);
}

#define YIX(R, K) yix2((R), (K))

#define MFMA3(ACC, AH, AL, BH, BL)                                        \
  ACC = __builtin_amdgcn_mfma_f32_16x16x32_bf16(AH, BH, ACC, 0, 0, 0);    \
  ACC = __builtin_amdgcn_mfma_f32_16x16x32_bf16(AH, BL, ACC, 0, 0, 0);    \
  ACC = __builtin_amdgcn_mfma_f32_16x16x32_bf16(AL, BH, ACC, 0, 0, 0);

__global__ __launch_bounds__(512, 1)
void ns_sqrt_kernel(const float* __restrict__ A, float* __restrict__ out) {
  __shared__ __align__(16) short Yhi[NN * NN];
  __shared__ __align__(16) short Ylo[NN * NN];
  __shared__ __align__(16) short Zhi[NN * NN];
  __shared__ __align__(16) short Zlo[NN * NN];
  __shared__ __align__(16) short Tq[2][2][NN * 32];  // [buf][hi=0/lo=1]

  // 163,840 B total == exactly the 160 KiB cap; red aliases Tq buf1.
  float* red = reinterpret_cast<float*>(&Tq[1][0][0]);

  const int tid  = threadIdx.x;
  const int wave = tid >> 6;
  const int lane = tid & 63;
  const int quad = lane >> 4;
  const int lrow = lane & 15;
  const int wr = wave >> 1, wc = wave & 1;
  const int RB = wr << 5, CB = wc << 6;   // 32x64 slab base

  #pragma unroll 1
  for (int sb = 0; sb < 2; ++sb) {
    const int b = (blockIdx.x << 1) + sb;
    const float* Ab = A + (size_t)b * (NN * NN);

    // ---- init: load all of A, Frobenius sum, store unnormalized split A ----
    float ss = 0.f;
    {
      const float4* p = reinterpret_cast<const float4*>(Ab);
      const int row = tid >> 2;          // 0..127
      const int c0  = (tid & 3) << 5;    // 0,32,64,96
      #pragma unroll
      for (int ch = 0; ch < 4; ++ch) {
        float4 v0 = p[row * (NN / 4) + (c0 >> 2) + (ch << 1) + 0];
        float4 v1 = p[row * (NN / 4) + (c0 >> 2) + (ch << 1) + 1];
        ss += v0.x * v0.x + v0.y * v0.y + v0.z * v0.z + v0.w * v0.w;
        ss += v1.x * v1.x + v1.y * v1.y + v1.z * v1.z + v1.w * v1.w;
        uint4 vh, vl;
        split_pair(v0.x, v0.y, vh.x, vl.x);
        split_pair(v0.z, v0.w, vh.y, vl.y);
        split_pair(v1.x, v1.y, vh.z, vl.z);
        split_pair(v1.z, v1.w, vh.w, vl.w);
        const int o = YIX(row, c0 + (ch << 3));
        *(uint4*)&Yhi[o] = vh;
        *(uint4*)&Ylo[o] = vl;
      }
    }
    #pragma unroll
    for (int off = 32; off; off >>= 1) ss += __shfl_xor(ss, off, 64);
    if (lane == 0) red[wave] = ss;
    __syncthreads();
    float tot = 0.f;
    #pragma unroll
    for (int w = 0; w < 8; ++w) tot += red[w];
    const float normA = sqrtf(tot);
    const float rn    = 1.f / normA;
    const float s_out = sqrtf(normA);

    const f32x4 zero4 = {0.f, 0.f, 0.f, 0.f};

    #pragma unroll 1
    for (int it = 1; it <= 5; ++it) {
      const bool doQ = (it >= 2) && (it <= 4);   // it1: Z1 = T; it5: Z unused
      f32x4 accM[2][4];
      f32x4 accP[2][4];
      f32x4 accQ[2][4];
      #pragma unroll
      for (int i = 0; i < 2; ++i)
        #pragma unroll
        for (int j = 0; j < 4; ++j) { accP[i][j] = zero4; accQ[i][j] = zero4; }

      if (it == 1) {
        // M = A slab (symmetric b64 read); normalization folded via mscale
        #pragma unroll
        for (int i = 0; i < 2; ++i)
          #pragma unroll
          for (int j = 0; j < 4; ++j) {
            const int col  = CB + 16*j + lrow;
            const int row0 = RB + 16*i + (quad << 2);
            const int o = YIX(col, row0);
            short4v h = *(const short4v*)&Yhi[o];
            short4v l = *(const short4v*)&Ylo[o];
            #pragma unroll
            for (int r = 0; r < 4; ++r) accM[i][j][r] = bf2f(h[r]) + bf2f(l[r]);
          }
      } else {
        // M = Z*Y  (A = Z rows; B = Y rows via symmetry)
        #pragma unroll
        for (int i = 0; i < 2; ++i)
          #pragma unroll
          for (int j = 0; j < 4; ++j) accM[i][j] = zero4;
        #pragma unroll
        for (int kc = 0; kc < 4; ++kc) {
          const int k0 = (kc << 5) + (quad << 3);
          bf16x8 ah[2], al[2], bh[4], bl[4];
          #pragma unroll
          for (int i = 0; i < 2; ++i) {
            const int o = YIX(RB + lrow + 16*i, k0);
            ah[i] = *(const bf16x8*)&Zhi[o];
            al[i] = *(const bf16x8*)&Zlo[o];
          }
          #pragma unroll
          for (int j = 0; j < 4; ++j) {
            const int o = YIX(CB + lrow + 16*j, k0);
            bh[j] = *(const bf16x8*)&Yhi[o];
            bl[j] = *(const bf16x8*)&Ylo[o];
          }
          #pragma unroll
          for (int i = 0; i < 2; ++i)
            #pragma unroll
            for (int j = 0; j < 4; ++j) { MFMA3(accM[i][j], ah[i], al[i], bh[j], bl[j]); }
        }
      }

      // T = 1.5 I - 0.5*mscale*M, split immediately into packed regs
      const float mscale = (it == 1) ? rn : 1.0f;
      unsigned tp[2][4][2], tl[2][4][2];
      #pragma unroll
      for (int i = 0; i < 2; ++i)
        #pragma unroll
        for (int j = 0; j < 4; ++j) {
          float tv[4];
          #pragma unroll
          for (int r = 0; r < 4; ++r) {
            float t0 = -0.5f * mscale * accM[i][j][r];
            if (RB + 16*i + (quad << 2) + r == CB + 16*j + lrow) t0 += 1.5f;
            tv[r] = t0;
          }
          split_pair(tv[0], tv[1], tp[i][j][0], tl[i][j][0]);
          split_pair(tv[2], tv[3], tp[i][j][1], tl[i][j][1]);
        }

      // 4 phases over 32-row blocks of T, double-buffered panels.
      // Phase t: wave wr==t stages buf[t&1] (prev readers drained at
      // barrier t-1), ONE publish barrier, everyone computes.
      #pragma unroll 1
      for (int t = 0; t < 4; ++t) {
        short* __restrict__ th = &Tq[t & 1][0][0];
        short* __restrict__ tg = &Tq[t & 1][1][0];

        if (wr == t) {
          #pragma unroll
          for (int i = 0; i < 2; ++i) {
            const int kp0 = (i << 4) + (quad << 2);
            #pragma unroll
            for (int j = 0; j < 4; ++j) {
              const int col = CB + 16*j + lrow;
              const int o = tix(col, kp0);
              *(uint2*)&th[o] = make_uint2(tp[i][j][0], tp[i][j][1]);
              *(uint2*)&tg[o] = make_uint2(tl[i][j][0], tl[i][j][1]);
            }
          }
        }

        // A-fragments depend only on Y/Z (stable all phase-loop long):
        // issued above the barrier so their latency hides under the wait.
        const int k0 = (t << 5) + (quad << 3);
        bf16x8 ahY[2], alY[2], ahZ[2], alZ[2];
        #pragma unroll
        for (int i = 0; i < 2; ++i) {
          const int o = YIX(RB + lrow + 16*i, k0);
          ahY[i] = *(const bf16x8*)&Yhi[o];
          alY[i] = *(const bf16x8*)&Ylo[o];
        }
        if (doQ) {
          #pragma unroll
          for (int i = 0; i < 2; ++i) {
            const int o = YIX(RB + lrow + 16*i, k0);
            ahZ[i] = *(const bf16x8*)&Zhi[o];
            alZ[i] = *(const bf16x8*)&Zlo[o];
          }
        }

        __syncthreads();                   // publish Tq[t&1]

        const int kq = quad << 3;
        bf16x8 bh[4], bl[4];
        #pragma unroll
        for (int j = 0; j < 4; ++j) {
          const int o = tix(CB + 16*j + lrow, kq);
          bh[j] = *(const bf16x8*)&th[o];
          bl[j] = *(const bf16x8*)&tg[o];
        }
        __builtin_amdgcn_s_setprio(1);
        #pragma unroll
        for (int i = 0; i < 2; ++i)
          #pragma unroll
          for (int j = 0; j < 4; ++j) { MFMA3(accP[i][j], ahY[i], alY[i], bh[j], bl[j]); }
        if (doQ) {
          #pragma unroll
          for (int i = 0; i < 2; ++i)
            #pragma unroll
            for (int j = 0; j < 4; ++j) { MFMA3(accQ[i][j], ahZ[i], alZ[i], bh[j], bl[j]); }
        }
        __builtin_amdgcn_s_setprio(0);
      }
      __syncthreads();   // all reads of Y/Z/Tq complete

      if (it < 5) {
        // write-back (packed b64 "transposed" store = same matrix by symmetry)
        const float yscale = (it == 1) ? rn : 1.0f;
        #pragma unroll
        for (int i = 0; i < 2; ++i)
          #pragma unroll
          for (int j = 0; j < 4; ++j) {
            const int col  = CB + 16*j + lrow;
            const int row0 = RB + 16*i + (quad << 2);
            const int o = YIX(col, row0);
            unsigned h01, l01, h23, l23;
            split_pair(yscale * accP[i][j][0], yscale * accP[i][j][1], h01, l01);
            split_pair(yscale * accP[i][j][2], yscale * accP[i][j][3], h23, l23);
            *(uint2*)&Yhi[o] = make_uint2(h01, h23);
            *(uint2*)&Ylo[o] = make_uint2(l01, l23);
            if (it == 1) {
              // Z1 = T: reuse the packed split regs directly
              *(uint2*)&Zhi[o] = make_uint2(tp[i][j][0], tp[i][j][1]);
              *(uint2*)&Zlo[o] = make_uint2(tl[i][j][0], tl[i][j][1]);
            } else {
              split_pair(accQ[i][j][0], accQ[i][j][1], h01, l01);
              split_pair(accQ[i][j][2], accQ[i][j][3], h23, l23);
              *(uint2*)&Zhi[o] = make_uint2(h01, h23);
              *(uint2*)&Zlo[o] = make_uint2(l01, l23);
            }
          }
        __syncthreads();
      } else {
        // final: out = Y5 * sqrt(normA)  (fire-and-forget; overlaps next init)
        float* ob = out + (size_t)b * (NN * NN);
        #pragma unroll
        for (int i = 0; i < 2; ++i)
          #pragma unroll
          for (int j = 0; j < 4; ++j) {
            const int col  = CB + 16*j + lrow;
            const int row0 = RB + 16*i + (quad << 2);
            #pragma unroll
            for (int r = 0; r < 4; ++r)
              ob[(size_t)(row0 + r) * NN + col] = accP[i][j][r] * s_out;
          }
      }
    }
  }
}

extern "C" void kernel_launch(void* const* d_in, const int* in_sizes, int n_in,
                              void* d_out, int out_size, void* d_ws, size_t ws_size,
                              hipStream_t stream) {
  const float* A = (const float*)d_in[0];
  float* out = (float*)d_out;
  ns_sqrt_kernel<<<dim3(512), dim3(512), 0, stream>>>(A, out);
}